// Round 1
// 905.380 us; speedup vs baseline: 1.1601x; 1.1601x over previous
//
#include <hip/hip_runtime.h>

typedef unsigned short u16;
typedef __attribute__((ext_vector_type(8))) short short8;
typedef __attribute__((ext_vector_type(8))) unsigned short us8;
typedef __attribute__((ext_vector_type(4))) unsigned short us4;
typedef __attribute__((ext_vector_type(4))) float f32x4;

namespace {

constexpr int Bn = 2, Sn = 2048, Dn = 1024, Hn = 16, DKn = 64;

__device__ __forceinline__ u16 f2bf(float f) {  // RNE fp32 -> bf16
  unsigned u = __builtin_bit_cast(unsigned, f);
  u += 0x7fffu + ((u >> 16) & 1u);
  return (u16)(u >> 16);
}
__device__ __forceinline__ float bf2f(u16 h) {
  unsigned u = ((unsigned)h) << 16;
  return __builtin_bit_cast(float, u);
}
__device__ __forceinline__ f32x4 mfma16(short8 a, short8 b, f32x4 c) {
  return __builtin_amdgcn_mfma_f32_16x16x32_bf16(a, b, c, 0, 0, 0);
}
__device__ __forceinline__ void gl_lds16(const void* g, void* l) {
  __builtin_amdgcn_global_load_lds(
      (const __attribute__((address_space(1))) void*)g,
      (__attribute__((address_space(3))) void*)l, 16, 0, 0);
}

// fp32 -> bf16 hi/lo planar split (hi = RNE(a), lo = RNE(a - hi))
__global__ __launch_bounds__(256, 4) void split_f32(
    const float* __restrict__ in, u16* __restrict__ hi, u16* __restrict__ lo, int n) {
  const int i = (blockIdx.x * 256 + threadIdx.x) * 4;
  if (i >= n) return;
  const float4 f = *(const float4*)(in + i);
  const float fs[4] = {f.x, f.y, f.z, f.w};
  us4 hv, lv;
#pragma unroll
  for (int j = 0; j < 4; j++) {
    const u16 h = f2bf(fs[j]);
    hv[j] = h;
    lv[j] = f2bf(fs[j] - bf2f(h));
  }
  *(us4*)(hi + i) = hv;
  *(us4*)(lo + i) = lv;
}

// C = A(4096xK) . B(1024xK)^T + bias, A/B bf16 planar hi(/lo).
// SPLIT: 3-MFMA split-precision (~fp32). OUTMODE: 0 = bf16 split-head q/k
// [B,H,S,DK]; 1 = bf16 v-transposed [B,H,DK,S]; 2 = fp32 [M,N] (d_out).
// Tile 128x128, BK=32, 4 waves, 16x16x32 MFMA, global_load_lds width=16.
template <bool SPLIT, int OUTMODE>
__global__ __launch_bounds__(256, 2) void proj_gemm(
    const u16* __restrict__ Ah, const u16* __restrict__ Al,
    const u16* __restrict__ Bh, const u16* __restrict__ Bl,
    const float* __restrict__ bias, void* __restrict__ outp) {
  constexpr int K = 1024, BK = 32;
  __shared__ u16 sAh[128 * BK];
  __shared__ u16 sBh[128 * BK];
  __shared__ u16 sAl[SPLIT ? 128 * BK : 16];
  __shared__ u16 sBl[SPLIT ? 128 * BK : 16];
  const int tid = threadIdx.x, l = tid & 63, w = tid >> 6;
  const int m0 = blockIdx.x * 128, n0 = blockIdx.y * 128;
  const int wr = (w >> 1) * 64, wc = (w & 1) * 64;
  const int lr = l & 15, la = l >> 4;
  const int r0 = tid >> 2, q0 = (tid & 3) * 8;
  const int c1 = tid + 256, r1 = c1 >> 2, q1 = (c1 & 3) * 8;
  f32x4 acc[4][4] = {};

  for (int k0 = 0; k0 < K; k0 += BK) {
    __syncthreads();  // previous compute done before restaging
    gl_lds16(Ah + (size_t)(m0 + r0) * K + k0 + q0, (char*)sAh + tid * 16);
    gl_lds16(Ah + (size_t)(m0 + r1) * K + k0 + q1, (char*)sAh + c1 * 16);
    gl_lds16(Bh + (size_t)(n0 + r0) * K + k0 + q0, (char*)sBh + tid * 16);
    gl_lds16(Bh + (size_t)(n0 + r1) * K + k0 + q1, (char*)sBh + c1 * 16);
    if (SPLIT) {
      gl_lds16(Al + (size_t)(m0 + r0) * K + k0 + q0, (char*)sAl + tid * 16);
      gl_lds16(Al + (size_t)(m0 + r1) * K + k0 + q1, (char*)sAl + c1 * 16);
      gl_lds16(Bl + (size_t)(n0 + r0) * K + k0 + q0, (char*)sBl + tid * 16);
      gl_lds16(Bl + (size_t)(n0 + r1) * K + k0 + q1, (char*)sBl + c1 * 16);
    }
    __syncthreads();  // drains vmcnt: staging complete

    short8 fah[4], fbh[4];
#pragma unroll
    for (int i = 0; i < 4; i++) {
      fah[i] = *(const short8*)&sAh[(wr + i * 16 + lr) * BK + la * 8];
      fbh[i] = *(const short8*)&sBh[(wc + i * 16 + lr) * BK + la * 8];
    }
    if (SPLIT) {
      short8 fal[4], fbl[4];
#pragma unroll
      for (int i = 0; i < 4; i++) {
        fal[i] = *(const short8*)&sAl[(wr + i * 16 + lr) * BK + la * 8];
        fbl[i] = *(const short8*)&sBl[(wc + i * 16 + lr) * BK + la * 8];
      }
#pragma unroll
      for (int i = 0; i < 4; i++)
#pragma unroll
        for (int j = 0; j < 4; j++) {
          acc[i][j] = mfma16(fah[i], fbh[j], acc[i][j]);
          acc[i][j] = mfma16(fah[i], fbl[j], acc[i][j]);
          acc[i][j] = mfma16(fal[i], fbh[j], acc[i][j]);
        }
    } else {
#pragma unroll
      for (int i = 0; i < 4; i++)
#pragma unroll
        for (int j = 0; j < 4; j++) acc[i][j] = mfma16(fah[i], fbh[j], acc[i][j]);
    }
  }

  // C/D layout: col = lane&15, row = (lane>>4)*4 + reg
#pragma unroll
  for (int i = 0; i < 4; i++)
#pragma unroll
    for (int j = 0; j < 4; j++)
#pragma unroll
      for (int r = 0; r < 4; r++) {
        const int m = m0 + wr + i * 16 + la * 4 + r;
        const int n = n0 + wc + j * 16 + lr;
        const float val = acc[i][j][r] + bias[n];
        if (OUTMODE == 0) {
          const int b = m >> 11, s = m & (Sn - 1), h = n >> 6, dk = n & 63;
          ((u16*)outp)[(((size_t)(b * Hn + h)) * Sn + s) * DKn + dk] = f2bf(val);
        } else if (OUTMODE == 1) {
          const int b = m >> 11, s = m & (Sn - 1), h = n >> 6, dk = n & 63;
          ((u16*)outp)[((size_t)(b * Hn + h) * DKn + dk) * Sn + s] = f2bf(val);
        } else {
          ((float*)outp)[(size_t)m * Dn + n] = val;
        }
      }
}

// Fused scores + softmax + PV, two-pass recompute (no raw-score
// materialization, no attn re-read). Grid (S/64 row-tiles, B*H).
// Pass 1: rowsum of exp(qk/8). Pass 2: recompute, normalize, write fp32
// attn once, AND consume the normalized P tile from LDS as the PV
// A-operand (bf16), accumulating ctx = P.V in registers. Numerically
// identical to the previous separate attn_pv kernel (same bf16-rounded
// P values, same summation order).
__global__ __launch_bounds__(256, 2) void scores_softmax_pv(
    const u16* __restrict__ q, const u16* __restrict__ kk,
    const u16* __restrict__ vT, float* __restrict__ attn,
    u16* __restrict__ chi, u16* __restrict__ clo) {
  __shared__ u16 lq[64 * 64];
  __shared__ u16 lk[64 * 64];
  __shared__ u16 lv[64 * 64];
  __shared__ float tile[64 * 68];  // stride 68: 16B-aligned rows
  __shared__ float rsum[64];
  const int tid = threadIdx.x, l = tid & 63, w = tid >> 6;
  const int bh = blockIdx.y, rt0 = blockIdx.x * 64;
  const int b = bh >> 4, h = bh & 15;
  const int lr = l & 15, la = l >> 4;
  if (tid < 64) rsum[tid] = 0.f;

  const u16* qbase = q + ((size_t)bh * Sn + rt0) * DKn;  // 8KB contiguous
  gl_lds16(qbase + tid * 8, (char*)lq + tid * 16);
  gl_lds16(qbase + (tid + 256) * 8, (char*)lq + (tid + 256) * 16);
  __syncthreads();
  short8 qa[4][2];
#pragma unroll
  for (int rt = 0; rt < 4; rt++) {
    qa[rt][0] = *(const short8*)&lq[(rt * 16 + lr) * 64 + la * 8];
    qa[rt][1] = *(const short8*)&lq[(rt * 16 + lr) * 64 + 32 + la * 8];
  }

  const u16* kb0 = kk + (size_t)bh * Sn * DKn;
  const u16* vb0 = vT + (size_t)bh * DKn * Sn;  // [DK=64, Sn]
  float psum[4][4] = {};
  for (int ct = 0; ct < 32; ++ct) {  // pass 1: rowsums
    __syncthreads();
    const u16* kbase = kb0 + (size_t)ct * 64 * DKn;
    gl_lds16(kbase + tid * 8, (char*)lk + tid * 16);
    gl_lds16(kbase + (tid + 256) * 8, (char*)lk + (tid + 256) * 16);
    __syncthreads();
    const short8 kv0 = *(const short8*)&lk[(w * 16 + lr) * 64 + la * 8];
    const short8 kv1 = *(const short8*)&lk[(w * 16 + lr) * 64 + 32 + la * 8];
#pragma unroll
    for (int rt = 0; rt < 4; rt++) {
      f32x4 sv = {};
      sv = mfma16(qa[rt][0], kv0, sv);
      sv = mfma16(qa[rt][1], kv1, sv);
#pragma unroll
      for (int r = 0; r < 4; r++) psum[rt][r] += __expf(sv[r] * 0.125f);
    }
  }
  // reduce over the 16 col-lanes, then across waves via LDS atomics
#pragma unroll
  for (int d = 1; d < 16; d <<= 1)
#pragma unroll
    for (int rt = 0; rt < 4; rt++)
#pragma unroll
      for (int r = 0; r < 4; r++) psum[rt][r] += __shfl_xor(psum[rt][r], d, 64);
  if (lr == 0) {
#pragma unroll
    for (int rt = 0; rt < 4; rt++)
#pragma unroll
      for (int r = 0; r < 4; r++)
        atomicAdd(&rsum[rt * 16 + la * 4 + r], psum[rt][r]);
  }
  __syncthreads();
  float inv[4][4];
#pragma unroll
  for (int rt = 0; rt < 4; rt++)
#pragma unroll
    for (int r = 0; r < 4; r++) inv[rt][r] = 1.0f / rsum[rt * 16 + la * 4 + r];

  float* abase = attn + (size_t)bh * Sn * Sn + (size_t)rt0 * Sn;
  const int srow = tid >> 2, scg = tid & 3;
  const int vr0 = tid >> 3, vq0 = (tid & 7) * 8;
  const int c1v = tid + 256, vr1 = c1v >> 3, vq1 = (c1v & 7) * 8;
  f32x4 cacc[4] = {};  // wave w owns q-rows w*16..+15; 4 dk col-frags
  for (int ct = 0; ct < 32; ++ct) {  // pass 2: attn write + PV
    __syncthreads();
    const u16* kbase = kb0 + (size_t)ct * 64 * DKn;
    gl_lds16(kbase + tid * 8, (char*)lk + tid * 16);
    gl_lds16(kbase + (tid + 256) * 8, (char*)lk + (tid + 256) * 16);
    gl_lds16(vb0 + (size_t)vr0 * Sn + ct * 64 + vq0, (char*)lv + tid * 16);
    gl_lds16(vb0 + (size_t)vr1 * Sn + ct * 64 + vq1, (char*)lv + c1v * 16);
    __syncthreads();
    const short8 kv0 = *(const short8*)&lk[(w * 16 + lr) * 64 + la * 8];
    const short8 kv1 = *(const short8*)&lk[(w * 16 + lr) * 64 + 32 + la * 8];
#pragma unroll
    for (int rt = 0; rt < 4; rt++) {
      f32x4 sv = {};
      sv = mfma16(qa[rt][0], kv0, sv);
      sv = mfma16(qa[rt][1], kv1, sv);
#pragma unroll
      for (int r = 0; r < 4; r++)
        tile[(rt * 16 + la * 4 + r) * 68 + w * 16 + lr] =
            __expf(sv[r] * 0.125f) * inv[rt][r];
    }
    __syncthreads();
    // coalesced fp32 attn store
    float* dst = abase + (size_t)srow * Sn + ct * 64 + scg * 16;
    const float* srcp = &tile[srow * 68 + scg * 16];
#pragma unroll
    for (int ii = 0; ii < 4; ii++)
      *(float4*)(dst + ii * 4) = *(const float4*)(srcp + ii * 4);
    // PV: A-fragments = bf16(P) rows of this wave's 16-row stripe
    const float* prow = &tile[(w * 16 + lr) * 68 + la * 8];
    us8 a0u, a1u;
#pragma unroll
    for (int t = 0; t < 8; t++) {
      a0u[t] = f2bf(prow[t]);
      a1u[t] = f2bf(prow[32 + t]);
    }
    const short8 pa0 = __builtin_bit_cast(short8, a0u);
    const short8 pa1 = __builtin_bit_cast(short8, a1u);
#pragma unroll
    for (int j = 0; j < 4; j++) {
      const short8 fb0 = *(const short8*)&lv[(j * 16 + lr) * 64 + la * 8];
      const short8 fb1 = *(const short8*)&lv[(j * 16 + lr) * 64 + 32 + la * 8];
      cacc[j] = mfma16(pa0, fb0, cacc[j]);
      cacc[j] = mfma16(pa1, fb1, cacc[j]);
    }
  }

  // ctx epilogue: hi/lo split for the output projection
#pragma unroll
  for (int j = 0; j < 4; j++)
#pragma unroll
    for (int r = 0; r < 4; r++) {
      const int s = rt0 + w * 16 + la * 4 + r;
      const int dd = h * 64 + j * 16 + lr;
      const size_t idx = ((size_t)(b * Sn + s)) * Dn + dd;
      const float v = cacc[j][r];
      const u16 hv = f2bf(v);
      chi[idx] = hv;
      clo[idx] = f2bf(v - bf2f(hv));
    }
}

}  // namespace

extern "C" void kernel_launch(void* const* d_in, const int* in_sizes, int n_in,
                              void* d_out, int out_size, void* d_ws, size_t ws_size,
                              hipStream_t stream) {
  (void)in_sizes; (void)n_in; (void)out_size; (void)ws_size;
  const float* x  = (const float*)d_in[0];
  const float* Wq = (const float*)d_in[1];
  const float* bq = (const float*)d_in[2];
  const float* Wk = (const float*)d_in[3];
  const float* bk = (const float*)d_in[4];
  const float* Wv = (const float*)d_in[5];
  const float* bv = (const float*)d_in[6];
  const float* Wo = (const float*)d_in[7];
  const float* bo = (const float*)d_in[8];

  float* out = (float*)d_out;
  float* attn = out + (size_t)Bn * Sn * Dn;

  char* ws = (char*)d_ws;
  auto MB = [](size_t m) { return m << 20; };
  u16* x_hi = (u16*)(ws);            // 8 MB
  u16* x_lo = (u16*)(ws + MB(8));    // 8 MB
  u16* wq_h = (u16*)(ws + MB(16));
  u16* wq_l = (u16*)(ws + MB(18));
  u16* wk_h = (u16*)(ws + MB(20));
  u16* wk_l = (u16*)(ws + MB(22));
  u16* wv_h = (u16*)(ws + MB(24));
  u16* wv_l = (u16*)(ws + MB(26));
  u16* wo_h = (u16*)(ws + MB(28));
  u16* wo_l = (u16*)(ws + MB(30));
  u16* qb = (u16*)(ws + MB(32));     // 8 MB bf16 [B,H,S,DK]
  u16* kb = (u16*)(ws + MB(40));     // 8 MB
  u16* vT = (u16*)(ws + MB(48));     // 8 MB bf16 [B,H,DK,S]
  u16* c_hi = x_hi;  // x dead after projections; reuse for ctx hi/lo
  u16* c_lo = x_lo;

  split_f32<<<4096, 256, 0, stream>>>(x, x_hi, x_lo, Bn * Sn * Dn);
  split_f32<<<1024, 256, 0, stream>>>(Wq, wq_h, wq_l, Dn * Dn);
  split_f32<<<1024, 256, 0, stream>>>(Wk, wk_h, wk_l, Dn * Dn);
  split_f32<<<1024, 256, 0, stream>>>(Wv, wv_h, wv_l, Dn * Dn);
  split_f32<<<1024, 256, 0, stream>>>(Wo, wo_h, wo_l, Dn * Dn);

  proj_gemm<true, 0><<<dim3(32, 8), 256, 0, stream>>>(x_hi, x_lo, wq_h, wq_l, bq, qb);
  proj_gemm<true, 0><<<dim3(32, 8), 256, 0, stream>>>(x_hi, x_lo, wk_h, wk_l, bk, kb);
  proj_gemm<false, 1><<<dim3(32, 8), 256, 0, stream>>>(x_hi, nullptr, wv_h, nullptr, bv, vT);

  scores_softmax_pv<<<dim3(32, 32), 256, 0, stream>>>(qb, kb, vT, attn, c_hi, c_lo);
  proj_gemm<true, 2><<<dim3(32, 8), 256, 0, stream>>>(c_hi, c_lo, wo_h, wo_l, bo, out);
}